// Round 1
// 828.733 us; speedup vs baseline: 1.1263x; 1.1263x over previous
//
#include <hip/hip_runtime.h>
#include <cstddef>
#include <cstdint>

// LinearQuantized: out = fake_quant_i8(x) @ fake_quant_i8(W)^T + bias
// x: [M=16384, K=4096] f32, W: [N=4096, K=4096] f32, bias: [N] f32, out: [M,N] f32
//
// v2: 256x256 i8 GEMM with the 8-phase-style schedule (T2 swizzle + T3/T4
// counted-vmcnt ring-4 pipeline + T5 setprio), replacing the 128x128
// 2-barrier-per-K-step structure (m97-ceiling, MfmaUtil 29%).

typedef int i32x4 __attribute__((ext_vector_type(4)));

__device__ __forceinline__ void async16(const void* g, void* l) {
    __builtin_amdgcn_global_load_lds(
        (const __attribute__((address_space(1))) void*)g,
        (__attribute__((address_space(3))) void*)l,
        16, 0, 0);
}

// ---------------- absmax reduction (unchanged, proven) ----------------
__global__ void absmax_kernel(const float* __restrict__ in, unsigned int n4,
                              unsigned int* __restrict__ out_bits) {
    const float4* in4 = (const float4*)in;
    float m = 0.0f;
    for (unsigned int i = blockIdx.x * blockDim.x + threadIdx.x; i < n4;
         i += gridDim.x * blockDim.x) {
        float4 v = in4[i];
        m = fmaxf(m, fmaxf(fmaxf(fabsf(v.x), fabsf(v.y)),
                           fmaxf(fabsf(v.z), fabsf(v.w))));
    }
    #pragma unroll
    for (int o = 32; o > 0; o >>= 1)
        m = fmaxf(m, __shfl_xor(m, o));
    __shared__ float wmax[8];
    int lane = threadIdx.x & 63;
    int wv = threadIdx.x >> 6;
    if (lane == 0) wmax[wv] = m;
    __syncthreads();
    if (threadIdx.x == 0) {
        int nw = blockDim.x >> 6;
        float b = wmax[0];
        for (int i = 1; i < nw; ++i) b = fmaxf(b, wmax[i]);
        // abs values are >= 0, so IEEE float order == uint order
        atomicMax(out_bits, __float_as_uint(b));
    }
}

// ---------------- quantize f32 -> i8 (now 16 B stores) ----------------
__device__ __forceinline__ int quant4(float4 v, float s) {
    int a = (int)fminf(fmaxf(rintf(v.x / s), -127.0f), 127.0f);
    int b = (int)fminf(fmaxf(rintf(v.y / s), -127.0f), 127.0f);
    int c = (int)fminf(fmaxf(rintf(v.z / s), -127.0f), 127.0f);
    int d = (int)fminf(fmaxf(rintf(v.w / s), -127.0f), 127.0f);
    return (a & 255) | ((b & 255) << 8) | ((c & 255) << 16) | (d << 24);
}

__global__ void quant_kernel(const float* __restrict__ in, char* __restrict__ out,
                             unsigned int n16,
                             const unsigned int* __restrict__ absmax_bits) {
    float s = fmaxf(__uint_as_float(*absmax_bits) / 127.0f, 1e-8f);
    const float4* in4 = (const float4*)in;
    i32x4* out16 = (i32x4*)out;
    for (unsigned int i = blockIdx.x * blockDim.x + threadIdx.x; i < n16;
         i += gridDim.x * blockDim.x) {
        float4 v0 = in4[i * 4 + 0];
        float4 v1 = in4[i * 4 + 1];
        float4 v2 = in4[i * 4 + 2];
        float4 v3 = in4[i * 4 + 3];
        i32x4 q;
        q[0] = quant4(v0, s);
        q[1] = quant4(v1, s);
        q[2] = quant4(v2, s);
        q[3] = quant4(v3, s);
        out16[i] = q;
    }
}

// ---------------- int8 GEMM, 256x256 tile, ring-4 pipelined ----------------
// 512 threads = 8 waves in 2(M) x 4(N); per-wave output 128x64.
// K-tile = 64 i8 cols (one mfma_i32_16x16x64_i8 K-step).
// LDS: ring of 4 K-tile slots per matrix, 16 KiB each -> 128 KiB total.
//   Slot layout (per matrix): 256 rows x 64 B, chunk-swizzled:
//   physical 16B-chunk = logical_chunk ^ ((row>>1)&3)   (involution)
//   -> ds_read_b128 of a 16-row column slice is 2-way bank aliased (free).
//   global_load_lds writes linearly; the swizzle is applied by permuting the
//   per-lane GLOBAL source chunk (rule: both-sides-or-neither).
// Schedule per K-tile t (2 phases x {ds_read, stage, bar, lgkmcnt0, 16 MFMA, bar}):
//   stage tile t+3 into slot (t+3)&3  (never aliases slot t&3 being read),
//   counted s_waitcnt vmcnt(8) once per tile boundary (2 tiles in flight),
//   raw s_barrier (no compiler vmcnt(0) drain).
#define BM 256
#define BN 256

__global__ __launch_bounds__(512, 2) void gemm_i8_kernel(
    const char* __restrict__ Aq, const char* __restrict__ Bq,
    const float* __restrict__ bias, float* __restrict__ C,
    const unsigned int* __restrict__ scale_bits, int M, int N, int K) {
    __shared__ char lds[4 * 16384 * 2];  // 128 KiB: sA slots then sB slots
    char* const sA = lds;
    char* const sB = lds + 4 * 16384;

    const int t = threadIdx.x;
    const int lane = t & 63;
    const int w = t >> 6;     // 0..7
    const int wm = w >> 2;    // 0..1
    const int wn = w & 3;     // 0..3

    const int m0 = blockIdx.y * BM;
    const int n0 = blockIdx.x * BN;

    // ---- staging source pointers (pre-swizzled chunk) ----
    // unit u in {0,1}: LDS offset o = u*8192 + t*16, row r = o>>6 = u*128 + t/4,
    // physical chunk = t&3, logical chunk = (t&3) ^ ((r>>1)&3) = (t&3)^((t>>3)&3)
    const int sr = t >> 2;                      // 0..127
    const int scl = (t & 3) ^ ((t >> 3) & 3);   // swizzled source chunk
    const char* gA0 = Aq + (size_t)(m0 + sr) * K + scl * 16;
    const char* gA1 = Aq + (size_t)(m0 + sr + 128) * K + scl * 16;
    const char* gB0 = Bq + (size_t)(n0 + sr) * K + scl * 16;
    const char* gB1 = Bq + (size_t)(n0 + sr + 128) * K + scl * 16;

#define STAGE_A(kt) do { char* d_ = sA + ((kt) & 3) * 16384 + t * 16;          \
        size_t ko_ = (size_t)(kt) * 64;                                        \
        async16(gA0 + ko_, d_); async16(gA1 + ko_, d_ + 8192); } while (0)
#define STAGE_B(kt) do { char* d_ = sB + ((kt) & 3) * 16384 + t * 16;          \
        size_t ko_ = (size_t)(kt) * 64;                                        \
        async16(gB0 + ko_, d_); async16(gB1 + ko_, d_ + 8192); } while (0)

    // ---- ds_read fragment addressing ----
    // A frag (16x64 i8): lane holds row (lane&15), k-chunk (lane>>4).
    const int rl = lane & 15;
    const int cg = lane >> 4;
    const int csw = (cg ^ ((rl >> 1) & 3)) << 4;    // swizzled chunk byte off
    const int aoff = wm * 8192 + rl * 64 + csw;     // + mtile*1024
    const int boff = wn * 4096 + rl * 64 + csw;     // + ntile*1024

    i32x4 acc[8][4] = {};

    const int NT = K >> 6;  // 64 K-tiles

    // ---- prologue: stage tiles 0,1,2; wait for tile 0 (8 = tiles 1,2 in flight)
    STAGE_A(0); STAGE_B(0);
    STAGE_A(1); STAGE_B(1);
    STAGE_A(2); STAGE_B(2);
    asm volatile("s_waitcnt vmcnt(8)" ::: "memory");
    __builtin_amdgcn_s_barrier();

#define MFMA_ROW(ai, AF)                                                        \
    acc[ai][0] = __builtin_amdgcn_mfma_i32_16x16x64_i8(AF, bf0, acc[ai][0], 0, 0, 0); \
    acc[ai][1] = __builtin_amdgcn_mfma_i32_16x16x64_i8(AF, bf1, acc[ai][1], 0, 0, 0); \
    acc[ai][2] = __builtin_amdgcn_mfma_i32_16x16x64_i8(AF, bf2, acc[ai][2], 0, 0, 0); \
    acc[ai][3] = __builtin_amdgcn_mfma_i32_16x16x64_i8(AF, bf3, acc[ai][3], 0, 0, 0);

    for (int kt = 0; kt < NT; ++kt) {
        const char* cA = sA + (kt & 3) * 16384;
        const char* cB = sB + (kt & 3) * 16384;

        // ===== phase 1: m-tiles 0..3, load all B frags =====
        i32x4 af0 = *(const i32x4*)(cA + aoff);
        i32x4 af1 = *(const i32x4*)(cA + aoff + 1024);
        i32x4 af2 = *(const i32x4*)(cA + aoff + 2048);
        i32x4 af3 = *(const i32x4*)(cA + aoff + 3072);
        i32x4 bf0 = *(const i32x4*)(cB + boff);
        i32x4 bf1 = *(const i32x4*)(cB + boff + 1024);
        i32x4 bf2 = *(const i32x4*)(cB + boff + 2048);
        i32x4 bf3 = *(const i32x4*)(cB + boff + 3072);
        if (kt + 3 < NT) STAGE_A(kt + 3);
        __builtin_amdgcn_s_barrier();
        asm volatile("s_waitcnt lgkmcnt(0)" ::: "memory");
        __builtin_amdgcn_sched_barrier(0);
        __builtin_amdgcn_s_setprio(1);
        MFMA_ROW(0, af0)
        MFMA_ROW(1, af1)
        MFMA_ROW(2, af2)
        MFMA_ROW(3, af3)
        __builtin_amdgcn_s_setprio(0);
        __builtin_amdgcn_s_barrier();

        // ===== phase 2: m-tiles 4..7, reuse B frags =====
        af0 = *(const i32x4*)(cA + aoff + 4096);
        af1 = *(const i32x4*)(cA + aoff + 5120);
        af2 = *(const i32x4*)(cA + aoff + 6144);
        af3 = *(const i32x4*)(cA + aoff + 7168);
        if (kt + 3 < NT) STAGE_B(kt + 3);
        __builtin_amdgcn_s_barrier();
        asm volatile("s_waitcnt lgkmcnt(0)" ::: "memory");
        __builtin_amdgcn_sched_barrier(0);
        __builtin_amdgcn_s_setprio(1);
        MFMA_ROW(4, af0)
        MFMA_ROW(5, af1)
        MFMA_ROW(6, af2)
        MFMA_ROW(7, af3)
        __builtin_amdgcn_s_setprio(0);
        // counted wait so next tile's ds_reads (after the barrier) are safe;
        // 2 tiles (8 loads/thread) stay in flight -- never drain in steady state
        if (kt < NT - 3) {
            asm volatile("s_waitcnt vmcnt(8)" ::: "memory");
        } else if (kt == NT - 3) {
            asm volatile("s_waitcnt vmcnt(4)" ::: "memory");
        } else if (kt == NT - 2) {
            asm volatile("s_waitcnt vmcnt(0)" ::: "memory");
        }
        __builtin_amdgcn_s_barrier();
    }

    // ---- epilogue ----
    float sx = fmaxf(__uint_as_float(scale_bits[0]) / 127.0f, 1e-8f);
    float sw = fmaxf(__uint_as_float(scale_bits[1]) / 127.0f, 1e-8f);
    float s = sx * sw;

    // C/D layout (16x16, shape-determined): col = lane&15, row = (lane>>4)*4 + reg
    const int crow = m0 + wm * 128 + cg * 4;
    const int ccol = n0 + wn * 64 + rl;
    #pragma unroll
    for (int nt = 0; nt < 4; ++nt) {
        int col = ccol + nt * 16;
        float bv = bias[col];
        #pragma unroll
        for (int mt = 0; mt < 8; ++mt) {
            float* Cp = C + (size_t)(crow + mt * 16) * N + col;
            #pragma unroll
            for (int r = 0; r < 4; ++r)
                Cp[(size_t)r * N] = (float)acc[mt][nt][r] * s + bv;
        }
    }
}

extern "C" void kernel_launch(void* const* d_in, const int* in_sizes, int n_in,
                              void* d_out, int out_size, void* d_ws, size_t ws_size,
                              hipStream_t stream) {
    const float* x = (const float*)d_in[0];
    const float* w = (const float*)d_in[1];
    const float* bias = (const float*)d_in[2];
    float* out = (float*)d_out;

    const int N = in_sizes[2];                 // 4096
    const int K = in_sizes[1] / N;             // 4096
    const int M = in_sizes[0] / K;             // 16384

    // workspace layout
    unsigned int* scale_bits = (unsigned int*)d_ws;  // [0]=absmax_x, [1]=absmax_w
    char* xq = (char*)d_ws + 256;                    // M*K int8
    char* wq = xq + (size_t)M * K;                   // N*K int8

    const unsigned int nx4 = (unsigned int)((size_t)M * K / 4);
    const unsigned int nw4 = (unsigned int)((size_t)N * K / 4);
    const unsigned int nx16 = nx4 / 4;
    const unsigned int nw16 = nw4 / 4;

    hipMemsetAsync(d_ws, 0, 16, stream);

    absmax_kernel<<<2048, 256, 0, stream>>>(x, nx4, scale_bits + 0);
    absmax_kernel<<<1024, 256, 0, stream>>>(w, nw4, scale_bits + 1);

    quant_kernel<<<2048, 256, 0, stream>>>(x, xq, nx16, scale_bits + 0);
    quant_kernel<<<1024, 256, 0, stream>>>(w, wq, nw16, scale_bits + 1);

    dim3 grid(N / BN, M / BM);
    gemm_i8_kernel<<<grid, 512, 0, stream>>>(xq, wq, bias, out, scale_bits, M, N, K);
}

// Round 2
// 807.640 us; speedup vs baseline: 1.1558x; 1.0261x over previous
//
#include <hip/hip_runtime.h>
#include <cstddef>
#include <cstdint>

// LinearQuantized: out = fake_quant_i8(x) @ fake_quant_i8(W)^T + bias
// x: [M=16384, K=4096] f32, W: [N=4096, K=4096] f32, bias: [N] f32, out: [M,N] f32
//
// v3: 256x256 i8 GEMM, mfma_i32_32x32x32_i8 (+12% ceiling vs 16x16x64),
// register-level fragment pipelining (read phase k+1 frags under phase k MFMAs,
// enabled by the ring-4 LDS), ONE barrier per K-tile, counted vmcnt(4).
// + XCD-chunked block swizzle, merged absmax/quant launches, NT loads in quant.

typedef int i32x4 __attribute__((ext_vector_type(4)));
typedef int i32x16 __attribute__((ext_vector_type(16)));
typedef float f32x4 __attribute__((ext_vector_type(4)));

__device__ __forceinline__ void async16(const void* g, void* l) {
    __builtin_amdgcn_global_load_lds(
        (const __attribute__((address_space(1))) void*)g,
        (__attribute__((address_space(3))) void*)l,
        16, 0, 0);
}

// ---------------- absmax reduction (x blocks 0..2047, w blocks 2048..2559) ----------------
__global__ void absmax2_kernel(const float* __restrict__ x, unsigned int nx4,
                               const float* __restrict__ w, unsigned int nw4,
                               unsigned int* __restrict__ out_bits) {
    const bool isW = (blockIdx.x >= 2048);
    const float4* in4 = (const float4*)(isW ? w : x);
    const unsigned int n4 = isW ? nw4 : nx4;
    const unsigned int stride = (isW ? 512u : 2048u) * blockDim.x;
    const unsigned int start =
        (isW ? (blockIdx.x - 2048) : blockIdx.x) * blockDim.x + threadIdx.x;
    float m = 0.0f;
    for (unsigned int i = start; i < n4; i += stride) {
        float4 v = in4[i];
        m = fmaxf(m, fmaxf(fmaxf(fabsf(v.x), fabsf(v.y)),
                           fmaxf(fabsf(v.z), fabsf(v.w))));
    }
    #pragma unroll
    for (int o = 32; o > 0; o >>= 1)
        m = fmaxf(m, __shfl_xor(m, o));
    __shared__ float wmax[4];
    int lane = threadIdx.x & 63;
    int wv = threadIdx.x >> 6;
    if (lane == 0) wmax[wv] = m;
    __syncthreads();
    if (threadIdx.x == 0) {
        int nw = blockDim.x >> 6;
        float b = wmax[0];
        for (int i = 1; i < nw; ++i) b = fmaxf(b, wmax[i]);
        // abs values are >= 0, so IEEE float order == uint order
        atomicMax(out_bits + (isW ? 1 : 0), __float_as_uint(b));
    }
}

// ---------------- quantize f32 -> i8, merged, NT loads ----------------
__device__ __forceinline__ int quant4(f32x4 v, float s) {
    int a = (int)fminf(fmaxf(rintf(v[0] / s), -127.0f), 127.0f);
    int b = (int)fminf(fmaxf(rintf(v[1] / s), -127.0f), 127.0f);
    int c = (int)fminf(fmaxf(rintf(v[2] / s), -127.0f), 127.0f);
    int d = (int)fminf(fmaxf(rintf(v[3] / s), -127.0f), 127.0f);
    return (a & 255) | ((b & 255) << 8) | ((c & 255) << 16) | (d << 24);
}

__global__ void quant2_kernel(const float* __restrict__ x, char* __restrict__ xq,
                              unsigned int nx16, const float* __restrict__ w,
                              char* __restrict__ wq, unsigned int nw16,
                              const unsigned int* __restrict__ scale_bits) {
    const bool isW = (blockIdx.x >= 2048);
    const f32x4* in4 = (const f32x4*)(isW ? w : x);
    i32x4* out16 = (i32x4*)(isW ? wq : xq);
    const unsigned int n16 = isW ? nw16 : nx16;
    const unsigned int stride = (isW ? 512u : 2048u) * blockDim.x;
    const unsigned int start =
        (isW ? (blockIdx.x - 2048) : blockIdx.x) * blockDim.x + threadIdx.x;
    float s = fmaxf(__uint_as_float(scale_bits[isW ? 1 : 0]) / 127.0f, 1e-8f);
    for (unsigned int i = start; i < n16; i += stride) {
        // NT loads: last use of f32 data -- don't evict the xq/wq the GEMM needs
        f32x4 v0 = __builtin_nontemporal_load(in4 + i * 4 + 0);
        f32x4 v1 = __builtin_nontemporal_load(in4 + i * 4 + 1);
        f32x4 v2 = __builtin_nontemporal_load(in4 + i * 4 + 2);
        f32x4 v3 = __builtin_nontemporal_load(in4 + i * 4 + 3);
        i32x4 q;
        q[0] = quant4(v0, s);
        q[1] = quant4(v1, s);
        q[2] = quant4(v2, s);
        q[3] = quant4(v3, s);
        out16[i] = q;
    }
}

// ---------------- int8 GEMM, 256x256 tile, 32x32x32 MFMA, reg-pipelined ----------------
// 512 threads = 8 waves in 2(M) x 4(N); per-wave output 128x64 = 4x2 tiles of 32x32.
// LDS: ring of 4 K-tile(BK=64) slots per matrix, 16 KiB each -> 128 KiB.
//   chunk swizzle: physical 16B-chunk = logical ^ ((row>>1)&3) (involution);
//   applied on the global SOURCE for staging (linear LDS dest) and on ds_read addr.
// Schedule per K-tile kt (ONE barrier):
//   PH1: ds_read A23(kt) | STAGE_A(kt+3) | MFMA m0,m1 (frags read last tile)
//   PH2: ds_read A01,B(kt+1)  <- slot kt+1 valid since end of kt-1 (vmcnt(4))
//        | STAGE_B(kt+3) | MFMA m2,m3 (A23 + current B)
//   vmcnt(4); s_barrier
#define BM 256
#define BN 256

__global__ __launch_bounds__(512, 2) void gemm_i8_kernel(
    const char* __restrict__ Aq, const char* __restrict__ Bq,
    const float* __restrict__ bias, float* __restrict__ C,
    const unsigned int* __restrict__ scale_bits, int M, int N, int K) {
    __shared__ char lds[4 * 16384 * 2];
    char* const sA = lds;
    char* const sB = lds + 4 * 16384;

    const int t = threadIdx.x;
    const int lane = t & 63;
    const int w = t >> 6;
    const int wm = w >> 2;    // 0..1
    const int wn = w & 3;     // 0..3

    // XCD-chunked bijective block swizzle (nwg = 1024, %8 == 0)
    const int nwgx = gridDim.x;                       // 16
    const int id = blockIdx.y * nwgx + blockIdx.x;
    const int cpx = (nwgx * gridDim.y) >> 3;
    const int swzid = (id & 7) * cpx + (id >> 3);
    const int m0 = (swzid / nwgx) * BM;
    const int n0 = (swzid % nwgx) * BN;

    // ---- staging (linear LDS dest, pre-swizzled global source chunk) ----
    const int sr = t >> 2;                      // 0..127
    const int scl = (t & 3) ^ ((t >> 3) & 3);   // swizzled source chunk
    const char* gA0 = Aq + (size_t)(m0 + sr) * K + scl * 16;
    const char* gA1 = Aq + (size_t)(m0 + sr + 128) * K + scl * 16;
    const char* gB0 = Bq + (size_t)(n0 + sr) * K + scl * 16;
    const char* gB1 = Bq + (size_t)(n0 + sr + 128) * K + scl * 16;

#define STAGE_A(kt) do { char* d_ = sA + ((kt) & 3) * 16384 + t * 16;          \
        size_t ko_ = (size_t)(kt) * 64;                                        \
        async16(gA0 + ko_, d_); async16(gA1 + ko_, d_ + 8192); } while (0)
#define STAGE_B(kt) do { char* d_ = sB + ((kt) & 3) * 16384 + t * 16;          \
        size_t ko_ = (size_t)(kt) * 64;                                        \
        async16(gB0 + ko_, d_); async16(gB1 + ko_, d_ + 8192); } while (0)

    // ---- ds_read fragment addressing (32x32x32: row = lane&31, k-half = lane>>5) ----
    const int rl32 = lane & 31;
    const int kh = lane >> 5;
    const int swz0 = ((kh ^ ((rl32 >> 1) & 3)) << 4);        // kstep 0: chunks 0,1
    const int swz1 = (((2 + kh) ^ ((rl32 >> 1) & 3)) << 4);  // kstep 1: chunks 2,3
    const int arow = wm * 8192 + rl32 * 64;   // + mt*2048
    const int brow = wn * 4096 + rl32 * 64;   // + j*2048

#define RD_A(slot, mt, s) (*(const i32x4*)((slot) + arow + (mt) * 2048 + ((s) ? swz1 : swz0)))
#define RD_B(slot, j, s)  (*(const i32x4*)((slot) + brow + (j) * 2048 + ((s) ? swz1 : swz0)))

    i32x16 acc[4][2] = {};
    i32x4 a00, a01, a10, a11;   // A m-tiles 0,1 (x kstep)
    i32x4 a20, a21, a30, a31;   // A m-tiles 2,3
    i32x4 p00, p01, p10, p11;   // B set P (j x kstep)
    i32x4 q00, q01, q10, q11;   // B set Q

    const int NT = K >> 6;  // 64

#define MM(acc_, a_, b_) acc_ = __builtin_amdgcn_mfma_i32_32x32x32_i8(a_, b_, acc_, 0, 0, 0)

#define PH1(cA_, kt3_, B00, B01, B10, B11)                                     \
    a20 = RD_A(cA_, 2, 0); a21 = RD_A(cA_, 2, 1);                              \
    a30 = RD_A(cA_, 3, 0); a31 = RD_A(cA_, 3, 1);                              \
    if ((kt3_) < NT) STAGE_A(kt3_);                                            \
    __builtin_amdgcn_sched_barrier(0);                                         \
    __builtin_amdgcn_s_setprio(1);                                             \
    MM(acc[0][0], a00, B00); MM(acc[0][1], a00, B10);                          \
    MM(acc[1][0], a10, B00); MM(acc[1][1], a10, B10);                          \
    MM(acc[0][0], a01, B01); MM(acc[0][1], a01, B11);                          \
    MM(acc[1][0], a11, B01); MM(acc[1][1], a11, B11);                          \
    __builtin_amdgcn_s_setprio(0);

#define PH2(cAn_, cBn_, kt3_, doRead_, B00, B01, B10, B11, N00, N01, N10, N11) \
    if (doRead_) {                                                             \
        a00 = RD_A(cAn_, 0, 0); a01 = RD_A(cAn_, 0, 1);                        \
        a10 = RD_A(cAn_, 1, 0); a11 = RD_A(cAn_, 1, 1);                        \
        N00 = RD_B(cBn_, 0, 0); N01 = RD_B(cBn_, 0, 1);                        \
        N10 = RD_B(cBn_, 1, 0); N11 = RD_B(cBn_, 1, 1);                        \
    }                                                                          \
    if ((kt3_) < NT) STAGE_B(kt3_);                                            \
    __builtin_amdgcn_sched_barrier(0);                                         \
    __builtin_amdgcn_s_setprio(1);                                             \
    MM(acc[2][0], a20, B00); MM(acc[2][1], a20, B10);                          \
    MM(acc[3][0], a30, B00); MM(acc[3][1], a30, B10);                          \
    MM(acc[2][0], a21, B01); MM(acc[2][1], a21, B11);                          \
    MM(acc[3][0], a31, B01); MM(acc[3][1], a31, B11);                          \
    __builtin_amdgcn_s_setprio(0);

#define TILE_END(kt_)                                                          \
    if ((kt_) + 3 < NT) { asm volatile("s_waitcnt vmcnt(4)" ::: "memory"); }   \
    else                { asm volatile("s_waitcnt vmcnt(0)" ::: "memory"); }   \
    __builtin_amdgcn_s_barrier();

    // ---- prologue: stage 0,1,2; ensure slots 0 AND 1 ready (vmcnt(4)) ----
    STAGE_A(0); STAGE_B(0);
    STAGE_A(1); STAGE_B(1);
    STAGE_A(2); STAGE_B(2);
    asm volatile("s_waitcnt vmcnt(4)" ::: "memory");
    __builtin_amdgcn_s_barrier();
    a00 = RD_A(sA, 0, 0); a01 = RD_A(sA, 0, 1);
    a10 = RD_A(sA, 1, 0); a11 = RD_A(sA, 1, 1);
    p00 = RD_B(sB, 0, 0); p01 = RD_B(sB, 0, 1);
    p10 = RD_B(sB, 1, 0); p11 = RD_B(sB, 1, 1);

    for (int kt = 0; kt < NT; kt += 2) {
        const char* cA0 = sA + ((kt) & 3) * 16384;
        const char* cA1 = sA + ((kt + 1) & 3) * 16384;
        const char* cB1 = sB + ((kt + 1) & 3) * 16384;
        const char* cA2 = sA + ((kt + 2) & 3) * 16384;
        const char* cB2 = sB + ((kt + 2) & 3) * 16384;

        // tile kt: consume B set P, prefetch next into Q
        PH1(cA0, kt + 3, p00, p01, p10, p11)
        PH2(cA1, cB1, kt + 3, 1, p00, p01, p10, p11, q00, q01, q10, q11)
        TILE_END(kt)

        // tile kt+1: consume B set Q, prefetch next into P
        PH1(cA1, kt + 4, q00, q01, q10, q11)
        PH2(cA2, cB2, kt + 4, (kt + 2 < NT), q00, q01, q10, q11, p00, p01, p10, p11)
        TILE_END(kt + 1)
    }

    // ---- epilogue ----
    float sx = fmaxf(__uint_as_float(scale_bits[0]) / 127.0f, 1e-8f);
    float sw = fmaxf(__uint_as_float(scale_bits[1]) / 127.0f, 1e-8f);
    float s = sx * sw;

    // 32x32 C/D layout: col = lane&31, row = (reg&3) + 8*(reg>>2) + 4*(lane>>5)
    const int rbase = m0 + wm * 128 + 4 * kh;
    const int cbase = n0 + wn * 64 + rl32;
    #pragma unroll
    for (int mt = 0; mt < 4; ++mt) {
        #pragma unroll
        for (int j = 0; j < 2; ++j) {
            int col = cbase + j * 32;
            float bv = bias[col];
            #pragma unroll
            for (int r = 0; r < 16; ++r) {
                int row = rbase + mt * 32 + (r & 3) + 8 * (r >> 2);
                C[(size_t)row * N + col] = (float)acc[mt][j][r] * s + bv;
            }
        }
    }
}

extern "C" void kernel_launch(void* const* d_in, const int* in_sizes, int n_in,
                              void* d_out, int out_size, void* d_ws, size_t ws_size,
                              hipStream_t stream) {
    const float* x = (const float*)d_in[0];
    const float* w = (const float*)d_in[1];
    const float* bias = (const float*)d_in[2];
    float* out = (float*)d_out;

    const int N = in_sizes[2];                 // 4096
    const int K = in_sizes[1] / N;             // 4096
    const int M = in_sizes[0] / K;             // 16384

    unsigned int* scale_bits = (unsigned int*)d_ws;  // [0]=absmax_x, [1]=absmax_w
    char* xq = (char*)d_ws + 256;                    // M*K int8
    char* wq = xq + (size_t)M * K;                   // N*K int8

    const unsigned int nx4 = (unsigned int)((size_t)M * K / 4);
    const unsigned int nw4 = (unsigned int)((size_t)N * K / 4);

    hipMemsetAsync(d_ws, 0, 16, stream);

    absmax2_kernel<<<2560, 256, 0, stream>>>(x, nx4, w, nw4, scale_bits);
    quant2_kernel<<<2560, 256, 0, stream>>>(x, xq, nx4 / 4, w, wq, nw4 / 4, scale_bits);

    dim3 grid(N / BN, M / BM);
    gemm_i8_kernel<<<grid, 512, 0, stream>>>(xq, wq, bias, out, scale_bits, M, N, K);
}